// Round 16
// baseline (171.989 us; speedup 1.0000x reference)
//
#include <hip/hip_runtime.h>
#include <hip/hip_fp16.h>
#include <math.h>

#define N_NODES 50000
#define N_EDGES 800000
#define E_TOT   (N_EDGES + N_NODES)
#define D_HID   64
#define N_CLS   40
#define SCAN_B  256
#define N_CHUNKS ((N_NODES + SCAN_B - 1) / SCAN_B)   // 196
#define NB      391                                   // dst buckets of 128 nodes
#define EPB     4096                                  // edges per pass-C block
#define EPG     1024                                  // edges per gemm128 block

struct __align__(8) H4 { __half2 a, b; };   // 4 halves = 8 bytes

typedef short bf16x8 __attribute__((ext_vector_type(8)));
typedef float f32x4  __attribute__((ext_vector_type(4)));

// ROCm 7.2 hip_fp16.h lacks __hmax2/__hmul2 — emit VOP3P packed ops directly.
__device__ __forceinline__ unsigned pk_max_f16(unsigned a, unsigned b) {
    unsigned r;
    asm("v_pk_max_f16 %0, %1, %2" : "=v"(r) : "v"(a), "v"(b));
    return r;
}
__device__ __forceinline__ unsigned pk_mul_f16(unsigned a, unsigned b) {
    unsigned r;
    asm("v_pk_mul_f16 %0, %1, %2" : "=v"(r) : "v"(a), "v"(b));
    return r;
}
__device__ __forceinline__ unsigned pkmax_xor(unsigned v, int o) {
    unsigned t = __shfl_xor((int)v, o, 64);
    return pk_max_f16(v, t);
}

// manual f32 -> bf16 round-to-nearest-even
__device__ __forceinline__ unsigned short f2bf(float f) {
    unsigned u = __float_as_uint(f);
    u += 0x7FFFu + ((u >> 16) & 1);
    return (unsigned short)(u >> 16);
}
__device__ __forceinline__ unsigned pk_bf(float a, float b) {
    return (unsigned)f2bf(a) | ((unsigned)f2bf(b) << 16);
}

// ---- CSR scan pass 1 --------------------------------------------------------
__device__ __forceinline__ int block_scan_incl(int v, int* wsum) {
    int lane = threadIdx.x & 63, w = threadIdx.x >> 6;
    int s = v;
#pragma unroll
    for (int d = 1; d < 64; d <<= 1) {
        int t = __shfl_up(s, d, 64);
        if (lane >= d) s += t;
    }
    if (lane == 63) wsum[w] = s;
    __syncthreads();
    int add = 0;
    for (int ww = 0; ww < (threadIdx.x >> 6); ++ww) add += wsum[ww];
    return s + add;
}

__global__ void k_scan1(const int* __restrict__ deg, int* __restrict__ rowptr,
                        int* __restrict__ partials) {
    __shared__ int wsum[4];
    int i = blockIdx.x * SCAN_B + threadIdx.x;
    int v = (i < N_NODES) ? deg[i] + 1 : 0;      // +1 = self loop
    int s = block_scan_incl(v, wsum);
    if (i < N_NODES) rowptr[i] = s - v;          // block-local exclusive
    if (threadIdx.x == SCAN_B - 1) partials[blockIdx.x] = s;
}

// ---- scan finalize: merges scan2 + scan3 + bucket_init ---------------------
__global__ void k_scan_fin(const int* __restrict__ partials, int* __restrict__ rowptr,
                           int* __restrict__ bcursor) {
    __shared__ int sp[SCAN_B];
    __shared__ int wsum[4];
    int t = threadIdx.x, b = blockIdx.x;
    int v = (t < N_CHUNKS) ? partials[t] : 0;
    int s = block_scan_incl(v, wsum);
    sp[t] = s - v;                               // exclusive prefix of partials
    __syncthreads();
    int add = sp[b];
    int i = b * SCAN_B + t;
    int r = 0;
    if (i < N_NODES) {
        r = rowptr[i] + add;
        rowptr[i] = r;
    }
    if (b == 0 && t == 0) rowptr[N_NODES] = E_TOT;
    if (t == 0)   bcursor[2 * b]     = r - ((2 * b) << 7);
    if (t == 128 && i < N_NODES) bcursor[2 * b + 1] = r - ((2 * b + 1) << 7);
}

// ---- pass C: bucket-grouping scatter (packed u32 pairs) --------------------
__global__ __launch_bounds__(256) void k_bucket_scatter(
        const unsigned* __restrict__ pairs_in, int* __restrict__ bcursor,
        unsigned* __restrict__ pairs_bkt) {
    __shared__ int counts[512];
    __shared__ int gbase[512];
    int t = threadIdx.x;
    counts[t] = 0; counts[t + 256] = 0;
    __syncthreads();
    int base = blockIdx.x * EPB;
    int nEdge = min(EPB, N_EDGES - base);
    unsigned pr[16];
    int rk[16], bk[16];
#define LOADI(i) { int idx = t + (i) * 256;                             \
        if (idx < nEdge) { pr[i] = pairs_in[base + idx];                \
            bk[i] = (pr[i] & 0xFFFF) >> 7;                              \
            rk[i] = atomicAdd(&counts[bk[i]], 1); } }
    LOADI(0) LOADI(1) LOADI(2) LOADI(3) LOADI(4) LOADI(5) LOADI(6) LOADI(7)
    LOADI(8) LOADI(9) LOADI(10) LOADI(11) LOADI(12) LOADI(13) LOADI(14) LOADI(15)
#undef LOADI
    __syncthreads();
    if (counts[t])       gbase[t]       = atomicAdd(&bcursor[t], counts[t]);
    if (counts[t + 256]) gbase[t + 256] = atomicAdd(&bcursor[t + 256], counts[t + 256]);
    __syncthreads();
#define STOREI(i) { int idx = t + (i) * 256;                            \
        if (idx < nEdge) pairs_bkt[gbase[bk[i]] + rk[i]] = pr[i]; }
    STOREI(0) STOREI(1) STOREI(2) STOREI(3) STOREI(4) STOREI(5) STOREI(6) STOREI(7)
    STOREI(8) STOREI(9) STOREI(10) STOREI(11) STOREI(12) STOREI(13) STOREI(14) STOREI(15)
#undef STOREI
}

// ---- pass D: within-bucket placement (LDS cursors, L2-resident writes) -----
__global__ __launch_bounds__(256) void k_bucket_place(
        const unsigned* __restrict__ pairs_bkt, const int* __restrict__ rowptr,
        int* __restrict__ src_sorted) {
    __shared__ int cur[128];
    int b = blockIdx.x, t = threadIdx.x;
    int d0 = b << 7;
    int dEnd = min(d0 + 128, N_NODES);
    if (t < 128) {
        int d = d0 + t;
        if (d < dEnd) {
            int r = rowptr[d];
            src_sorted[r] = d;            // self loop (order within segment free)
            cur[t] = r + 1;
        }
    }
    __syncthreads();
    int pbase = rowptr[d0] - d0;
    int pend  = rowptr[dEnd] - dEnd;
    for (int idx = pbase + t; idx < pend; idx += 256) {
        unsigned p = pairs_bkt[idx];
        int pos = atomicAdd(&cur[(p & 0xFFFF) - d0], 1);
        src_sorted[pos] = (int)(p >> 16);
    }
}

// ---- MFMA GEMM: WhH(fp16) = x@W (+ alpha dots; DOCONV: + edge convert) -----
template<int K, int DOCONV, int INBF16>
__global__ __launch_bounds__(256) void k_gemm_alpha(
        const void* __restrict__ xv, const float* __restrict__ W,
        const float* __restrict__ aW,
        H4* __restrict__ WhH,
        float* __restrict__ alpha_s, float* __restrict__ alpha_t,
        const void* ei, unsigned* __restrict__ pairs, int* __restrict__ deg) {
    __shared__ unsigned short xb[64][K + 8];
    __shared__ unsigned short wt[64][K + 8];
    __shared__ int s_is32;
    int tid = threadIdx.x;
    int rowBase = blockIdx.x * 64;

    if (INBF16) {
        int rr = tid >> 2;
        int kc = (tid & 3) * 16;                 // 16 bf16 = 32B per thread
        const unsigned short* xr = (const unsigned short*)xv
            + (size_t)min(rowBase + rr, N_NODES - 1) * 64 + kc;
        *(uint4*)&xb[rr][kc]     = *(const uint4*)xr;
        *(uint4*)&xb[rr][kc + 8] = *(const uint4*)(xr + 8);
    } else {
        int rr = tid >> 2;
        int kc = (tid & 3) * (K / 4);
        const float* xr = (const float*)xv + (size_t)min(rowBase + rr, N_NODES - 1) * K + kc;
        unsigned* dst = (unsigned*)&xb[rr][kc];
#pragma unroll
        for (int j = 0; j < K / 4; j += 8) {
            float4 v0 = *(const float4*)(xr + j);
            float4 v1 = *(const float4*)(xr + j + 4);
            dst[j / 2 + 0] = pk_bf(v0.x, v0.y);
            dst[j / 2 + 1] = pk_bf(v0.z, v0.w);
            dst[j / 2 + 2] = pk_bf(v1.x, v1.y);
            dst[j / 2 + 3] = pk_bf(v1.z, v1.w);
        }
    }
    for (int i = tid; i < K * 64; i += 256) {
        int k = i >> 6, n = i & 63;
        wt[n][k] = f2bf(W[i]);
    }
    if (DOCONV && tid == 0) s_is32 = 0;
    __syncthreads();

    int w = tid >> 6, lane = tid & 63;
    int la = lane & 15, hi = lane >> 4;

    f32x4 acc[4];
#pragma unroll
    for (int c = 0; c < 4; ++c) acc[c] = (f32x4){0.f, 0.f, 0.f, 0.f};

#pragma unroll
    for (int t = 0; t < K / 32; ++t) {
        int k0 = t * 32 + hi * 8;
        bf16x8 af = *(const bf16x8*)&xb[w * 16 + la][k0];
#pragma unroll
        for (int c = 0; c < 4; ++c) {
            bf16x8 bfr = *(const bf16x8*)&wt[c * 16 + la][k0];
            acc[c] = __builtin_amdgcn_mfma_f32_16x16x32_bf16(af, bfr, acc[c], 0, 0, 0);
        }
    }

    float as4[4], at4[4];
#pragma unroll
    for (int c = 0; c < 4; ++c) {
        as4[c] = aW[c * 16 + la];
        at4[c] = aW[64 + c * 16 + la];
    }
#pragma unroll
    for (int r = 0; r < 4; ++r) {
        int row = rowBase + w * 16 + hi * 4 + r;
        float ps = acc[0][r] * as4[0] + acc[1][r] * as4[1]
                 + acc[2][r] * as4[2] + acc[3][r] * as4[3];
        float pt = acc[0][r] * at4[0] + acc[1][r] * at4[1]
                 + acc[2][r] * at4[2] + acc[3][r] * at4[3];
#pragma unroll
        for (int o = 1; o < 16; o <<= 1) {
            ps += __shfl_xor(ps, o, 64);
            pt += __shfl_xor(pt, o, 64);
        }
        if (row < N_NODES) {
            __half* wr = (__half*)&WhH[(size_t)row * 16];
#pragma unroll
            for (int c = 0; c < 4; ++c)
                wr[c * 16 + la] = __float2half(acc[c][r]);
            if (la == 0) { alpha_s[row] = ps; alpha_t[row] = pt; }
        }
    }

    // fused edge convert (packed u32) + deg histogram (layer-1 only)
    if (DOCONV) {
        const int* p32 = (const int*)ei;
        if (p32[2 * tid + 1] != 0) atomicOr(&s_is32, 1);
        __syncthreads();
        int is32 = s_is32;
        int base = blockIdx.x * EPG;
#pragma unroll
        for (int i = 0; i < EPG / 256; ++i) {
            int e = base + tid + i * 256;
            if (e < N_EDGES) {
                int s, d;
                if (is32) {
                    s = p32[e]; d = p32[N_EDGES + e];
                } else {
                    const long long* p64 = (const long long*)ei;
                    s = (int)p64[e]; d = (int)p64[N_EDGES + e];
                }
                pairs[e] = ((unsigned)s << 16) | (unsigned)d;
                atomicAdd(&deg[d], 1);
            }
        }
    }
}

// ---- slow path helper (deg > 64): chunked two-pass, scalar fp16 gather -----
__device__ void slow_node(int rs, int re, const int* __restrict__ src_sorted,
                          const float* __restrict__ alpha_s, float at,
                          const H4* __restrict__ WhH, int lane, int fl2,
                          float& z, unsigned vm[4]) {
    float m = -INFINITY;
    for (int base = rs; base < re; base += 64) {
        int idx = base + lane;
        float sim = -INFINITY;
        if (idx < re) {
            int sv = src_sorted[idx];
            float t = alpha_s[sv] + at;
            sim = t > 0.f ? t : 0.2f * t;
        }
#pragma unroll
        for (int o = 32; o; o >>= 1) sim = fmaxf(sim, __shfl_xor(sim, o, 64));
        m = fmaxf(m, sim);
    }
    z = 0.f;
    float vsc = -INFINITY;
    for (int base = rs; base < re; base += 64) {
        int idx = base + lane;
        int cnt = min(64, re - base);
        int svv = 0;
        float ev = 0.f;
        if (idx < re) {
            svv = src_sorted[idx];
            float t = alpha_s[svv] + at;
            t = t > 0.f ? t : 0.2f * t;
            ev = __expf(t - m);
        }
        float sz = ev;
#pragma unroll
        for (int o = 32; o; o >>= 1) sz += __shfl_xor(sz, o, 64);
        z += sz;
        for (int j = 0; j < cnt; ++j) {
            int sj = __shfl(svv, j, 64);
            float ej = __shfl(ev, j, 64);
            float v = __half2float(((const __half*)WhH)[(size_t)sj * 64 + lane]);
            vsc = fmaxf(vsc, ej * v);
        }
    }
#pragma unroll
    for (int q = 0; q < 4; ++q) {
        float a0 = __shfl(vsc, fl2 * 8 + 2 * q, 64);
        float a1 = __shfl(vsc, fl2 * 8 + 2 * q + 1, 64);
        __half2 p = __floats2half2_rn(a0, a1);
        vm[q] = *(unsigned*)&p;
    }
}

// ---- per-dst-node fused aggregation: FOUR nodes per wave -------------------
// Extends R9's proven node-multiplexing (1->2 gave +11%): 4 interleaved round
// streams -> 4 independent gathers in flight. Same ROUND macro, same tiers.
template<int HEAD>
__global__ void k_node_aggr(const int* __restrict__ rowptr, const int* __restrict__ src_sorted,
                            const float* __restrict__ alpha_s, const float* __restrict__ alpha_t,
                            const float* __restrict__ ab, const H4* __restrict__ WhH,
                            const float* __restrict__ bias,
                            const float* __restrict__ Wo, const float* __restrict__ bo,
                            void* __restrict__ outp) {
    __shared__ float sWo[HEAD ? 64 * N_CLS : 1];
    __shared__ float sh[HEAD ? 16 * 64 : 1];
    int lane = threadIdx.x, w = threadIdx.y;
    if (HEAD) {
        int tid = w * 64 + lane;
        for (int i = tid; i < 64 * N_CLS; i += 256) sWo[i] = Wo[i];
    }
    int dA = blockIdx.x * 16 + w * 4;      // grid exact: 3125*16 == N_NODES
    int dB = dA + 1, dC = dA + 2, dD = dA + 3;
    int rsA = rowptr[dA], reA = rowptr[dA + 1];
    int rsB = rowptr[dB], reB = rowptr[dB + 1];
    int rsC = rowptr[dC], reC = rowptr[dC + 1];
    int rsD = rowptr[dD], reD = rowptr[dD + 1];
    int degA = reA - rsA, degB = reB - rsB;
    int degC = reC - rsC, degD = reD - rsD;
    float abv = ab[0];
    float atA = alpha_t[dA] + abv, atB = alpha_t[dB] + abv;
    float atC = alpha_t[dC] + abv, atD = alpha_t[dD] + abv;
    int g2 = lane >> 3, fl2 = lane & 7;
    const char* whb = (const char*)WhH;

    float zA, zB, zC, zD;
    unsigned vmA[4], vmB[4], vmC[4], vmD[4];

    if (degA <= 64 && degB <= 64 && degC <= 64 && degD <= 64) {
        // --- quad fast path ---
        int svA = src_sorted[rsA + min(lane, degA - 1)];
        int svB = src_sorted[rsB + min(lane, degB - 1)];
        int svC = src_sorted[rsC + min(lane, degC - 1)];
        int svD = src_sorted[rsD + min(lane, degD - 1)];
        float tA = alpha_s[svA] + atA; tA = tA > 0.f ? tA : 0.2f * tA;
        float tB = alpha_s[svB] + atB; tB = tB > 0.f ? tB : 0.2f * tB;
        float tC = alpha_s[svC] + atC; tC = tC > 0.f ? tC : 0.2f * tC;
        float tD = alpha_s[svD] + atD; tD = tD > 0.f ? tD : 0.2f * tD;
        float evA = __expf(tA), evB = __expf(tB);
        float evC = __expf(tC), evD = __expf(tD);
        float zzA = (lane < degA) ? evA : 0.f;
        float zzB = (lane < degB) ? evB : 0.f;
        float zzC = (lane < degC) ? evC : 0.f;
        float zzD = (lane < degD) ? evD : 0.f;
#pragma unroll
        for (int o = 32; o; o >>= 1) {
            zzA += __shfl_xor(zzA, o, 64);
            zzB += __shfl_xor(zzB, o, 64);
            zzC += __shfl_xor(zzC, o, 64);
            zzD += __shfl_xor(zzD, o, 64);
        }
        zA = zzA; zB = zzB; zC = zzC; zD = zzD;
        int ofsA = svA * 128, ofsB = svB * 128;
        int ofsC = svC * 128, ofsD = svD * 128;

        const unsigned NEGINF2 = 0xFC00FC00u;     // {-inf,-inf} fp16
        unsigned vA0 = NEGINF2, vA1 = NEGINF2, vA2 = NEGINF2, vA3 = NEGINF2;
        unsigned vB0 = NEGINF2, vB1 = NEGINF2, vB2 = NEGINF2, vB3 = NEGINF2;
        unsigned vC0 = NEGINF2, vC1 = NEGINF2, vC2 = NEGINF2, vC3 = NEGINF2;
        unsigned vD0 = NEGINF2, vD1 = NEGINF2, vD2 = NEGINF2, vD3 = NEGINF2;
#define ROUND(ev, ofs, deg, v0, v1, v2, v3, r) { \
        int j = (r) * 8 + g2; j = j < (deg) ? j : (deg) - 1;              \
        float ej = __shfl((ev), j, 64);                                   \
        int ro = __shfl((ofs), j, 64);                                    \
        uint4 hv = *(const uint4*)(whb + ro + fl2 * 16);                  \
        __half2 ejh = __float2half2_rn(ej);                               \
        unsigned ej2 = *(unsigned*)&ejh;                                  \
        v0 = pk_max_f16(v0, pk_mul_f16(ej2, hv.x));                       \
        v1 = pk_max_f16(v1, pk_mul_f16(ej2, hv.y));                       \
        v2 = pk_max_f16(v2, pk_mul_f16(ej2, hv.z));                       \
        v3 = pk_max_f16(v3, pk_mul_f16(ej2, hv.w)); }
#define RA(r) ROUND(evA, ofsA, degA, vA0, vA1, vA2, vA3, r)
#define RB(r) ROUND(evB, ofsB, degB, vB0, vB1, vB2, vB3, r)
#define RC(r) ROUND(evC, ofsC, degC, vC0, vC1, vC2, vC3, r)
#define RD(r) ROUND(evD, ofsD, degD, vD0, vD1, vD2, vD3, r)

        RA(0) RB(0) RC(0) RD(0)
        RA(1) RB(1) RC(1) RD(1)
        if (degA > 16) { RA(2) RA(3) }
        if (degB > 16) { RB(2) RB(3) }
        if (degC > 16) { RC(2) RC(3) }
        if (degD > 16) { RD(2) RD(3) }
        if (degA > 32) { RA(4) RA(5) RA(6) RA(7) }
        if (degB > 32) { RB(4) RB(5) RB(6) RB(7) }
        if (degC > 32) { RC(4) RC(5) RC(6) RC(7) }
        if (degD > 32) { RD(4) RD(5) RD(6) RD(7) }
#undef RA
#undef RB
#undef RC
#undef RD
#undef ROUND
#pragma unroll
        for (int o = 8; o <= 32; o <<= 1) {
            vA0 = pkmax_xor(vA0, o); vA1 = pkmax_xor(vA1, o);
            vA2 = pkmax_xor(vA2, o); vA3 = pkmax_xor(vA3, o);
            vB0 = pkmax_xor(vB0, o); vB1 = pkmax_xor(vB1, o);
            vB2 = pkmax_xor(vB2, o); vB3 = pkmax_xor(vB3, o);
            vC0 = pkmax_xor(vC0, o); vC1 = pkmax_xor(vC1, o);
            vC2 = pkmax_xor(vC2, o); vC3 = pkmax_xor(vC3, o);
            vD0 = pkmax_xor(vD0, o); vD1 = pkmax_xor(vD1, o);
            vD2 = pkmax_xor(vD2, o); vD3 = pkmax_xor(vD3, o);
        }
        vmA[0] = vA0; vmA[1] = vA1; vmA[2] = vA2; vmA[3] = vA3;
        vmB[0] = vB0; vmB[1] = vB1; vmB[2] = vB2; vmB[3] = vB3;
        vmC[0] = vC0; vmC[1] = vC1; vmC[2] = vC2; vmC[3] = vC3;
        vmD[0] = vD0; vmD[1] = vD1; vmD[2] = vD2; vmD[3] = vD3;
    } else {
        slow_node(rsA, reA, src_sorted, alpha_s, atA, WhH, lane, fl2, zA, vmA);
        slow_node(rsB, reB, src_sorted, alpha_s, atB, WhH, lane, fl2, zB, vmB);
        slow_node(rsC, reC, src_sorted, alpha_s, atC, WhH, lane, fl2, zC, vmC);
        slow_node(rsD, reD, src_sorted, alpha_s, atD, WhH, lane, fl2, zD, vmD);
    }

    // epilogue per node: h = vmax/z + bias, relu.
    float4 b0 = *(const float4*)(bias + fl2 * 8);
    float4 b1 = *(const float4*)(bias + fl2 * 8 + 4);
    float bias8[8] = { b0.x, b0.y, b0.z, b0.w, b1.x, b1.y, b1.z, b1.w };
    float rz[4] = { 1.0f / zA, 1.0f / zB, 1.0f / zC, 1.0f / zD };
    float h8[4][8];
#pragma unroll
    for (int q = 0; q < 4; ++q) {
        float2 fa = __half22float2(*(__half2*)&vmA[q]);
        float2 fb = __half22float2(*(__half2*)&vmB[q]);
        float2 fc = __half22float2(*(__half2*)&vmC[q]);
        float2 fd = __half22float2(*(__half2*)&vmD[q]);
        h8[0][2 * q] = fa.x; h8[0][2 * q + 1] = fa.y;
        h8[1][2 * q] = fb.x; h8[1][2 * q + 1] = fb.y;
        h8[2][2 * q] = fc.x; h8[2][2 * q + 1] = fc.y;
        h8[3][2 * q] = fd.x; h8[3][2 * q + 1] = fd.y;
    }
#pragma unroll
    for (int n = 0; n < 4; ++n)
#pragma unroll
        for (int q = 0; q < 8; ++q)
            h8[n][q] = fmaxf(h8[n][q] * rz[n] + bias8[q], 0.f);

    if (!HEAD) {
        // bf16 h_mid rows; group g2=n stores node n (n<4); groups 4-7 idle
        unsigned short* hm = (unsigned short*)outp;
        if (g2 < 4) {
            uint4 v;
            v.x = pk_bf(h8[g2][0], h8[g2][1]); v.y = pk_bf(h8[g2][2], h8[g2][3]);
            v.z = pk_bf(h8[g2][4], h8[g2][5]); v.w = pk_bf(h8[g2][6], h8[g2][7]);
            *(uint4*)(hm + (size_t)(dA + g2) * 64 + fl2 * 8) = v;
        }
    } else {
        float* op = (float*)outp;
        if (g2 < 4) {
            float* sp = sh + (4 * w + g2) * 64 + fl2 * 8;
            *(float4*)sp = make_float4(h8[g2][0], h8[g2][1], h8[g2][2], h8[g2][3]);
            *(float4*)(sp + 4) = make_float4(h8[g2][4], h8[g2][5], h8[g2][6], h8[g2][7]);
        }
        __syncthreads();
#pragma unroll
        for (int n = 0; n < 4; ++n) {
            int dd = dA + n;
            const float* hrow = sh + (4 * w + n) * 64;
            float logit = -INFINITY;
            if (lane < N_CLS) {
                float acc = bo[lane];
#pragma unroll
                for (int k = 0; k < 64; ++k)
                    acc = fmaf(hrow[k], sWo[k * N_CLS + lane], acc);
                logit = acc;
            }
            float mx = logit;
#pragma unroll
            for (int o = 32; o; o >>= 1) mx = fmaxf(mx, __shfl_xor(mx, o, 64));
            float ex = (lane < N_CLS) ? __expf(logit - mx) : 0.f;
            float sm = ex;
#pragma unroll
            for (int o = 32; o; o >>= 1) sm += __shfl_xor(sm, o, 64);
            float lse = mx + __logf(sm);
            if (lane < N_CLS) op[(size_t)dd * N_CLS + lane] = logit - lse;
        }
    }
}

extern "C" void kernel_launch(void* const* d_in, const int* in_sizes, int n_in,
                              void* d_out, int out_size, void* d_ws, size_t ws_size,
                              hipStream_t stream) {
    const float* x   = (const float*)d_in[0];
    const void*  ei  = d_in[1];
    const float* W1  = (const float*)d_in[2];
    const float* aW1 = (const float*)d_in[3];
    const float* ab1 = (const float*)d_in[4];
    const float* b1  = (const float*)d_in[5];
    const float* W2  = (const float*)d_in[6];
    const float* aW2 = (const float*)d_in[7];
    const float* ab2 = (const float*)d_in[8];
    const float* b2  = (const float*)d_in[9];
    const float* Wo  = (const float*)d_in[10];
    const float* bo  = (const float*)d_in[11];
    float* out = (float*)d_out;

    char* ws = (char*)d_ws;
    size_t off = 0;
    auto alloc = [&](size_t bytes) {
        void* p = ws + off;
        off += (bytes + 255) & ~(size_t)255;
        return p;
    };
    unsigned* pairs     = (unsigned*)alloc((size_t)N_EDGES * 4);
    unsigned* pairs_bkt = (unsigned*)alloc((size_t)N_EDGES * 4);
    int*   deg        = (int*)alloc((size_t)N_NODES * 4);
    int*   rowptr     = (int*)alloc((size_t)(N_NODES + 1) * 4);
    int*   bcursor    = (int*)alloc((size_t)512 * 4);
    int*   partials   = (int*)alloc((size_t)SCAN_B * 4);
    int*   src_sorted = (int*)alloc((size_t)E_TOT * 4);
    H4*    WhH        = (H4*)alloc((size_t)N_NODES * 64 * 2);
    unsigned short* h_mid = (unsigned short*)alloc((size_t)N_NODES * 64 * 2);
    float* alpha_s    = (float*)alloc((size_t)N_NODES * 4);
    float* alpha_t    = (float*)alloc((size_t)N_NODES * 4);

    const int B = 256;
    int gPassC = (N_EDGES + EPB - 1) / EPB;   // 196
    dim3 blk2(64, 4);
    int gRow  = N_NODES / 16;           // 3125, exact (4 nodes/wave)
    int gGemm = (N_NODES + 63) / 64;    // 782

    hipMemsetAsync(deg, 0, (size_t)N_NODES * 4, stream);

    // ---- layer-1 GEMM fused with edge convert + deg histogram
    k_gemm_alpha<128, 1, 0><<<gGemm, 256, 0, stream>>>(x, W1, aW1, WhH, alpha_s, alpha_t,
                                                       ei, pairs, deg);
    // ---- CSR build
    k_scan1<<<N_CHUNKS, SCAN_B, 0, stream>>>(deg, rowptr, partials);
    k_scan_fin<<<N_CHUNKS, SCAN_B, 0, stream>>>(partials, rowptr, bcursor);
    k_bucket_scatter<<<gPassC, B, 0, stream>>>(pairs, bcursor, pairs_bkt);
    k_bucket_place<<<NB, B, 0, stream>>>(pairs_bkt, rowptr, src_sorted);

    // ---- layer 1 aggregation (writes bf16 h_mid)
    k_node_aggr<0><<<gRow, blk2, 0, stream>>>(rowptr, src_sorted, alpha_s, alpha_t,
                                              ab1, WhH, b1, nullptr, nullptr, h_mid);

    // ---- layer 2 (+ fused output head)
    k_gemm_alpha<64, 0, 1><<<gGemm, 256, 0, stream>>>(h_mid, W2, aW2, WhH, alpha_s, alpha_t,
                                                      nullptr, nullptr, nullptr);
    k_node_aggr<1><<<gRow, blk2, 0, stream>>>(rowptr, src_sorted, alpha_s, alpha_t,
                                              ab2, WhH, b2, Wo, bo, out);
}

// Round 17
// 155.190 us; speedup vs baseline: 1.1082x; 1.1082x over previous
//
#include <hip/hip_runtime.h>
#include <hip/hip_fp16.h>
#include <math.h>

#define N_NODES 50000
#define N_EDGES 800000
#define E_TOT   (N_EDGES + N_NODES)
#define D_HID   64
#define N_CLS   40
#define SCAN_B  256
#define N_CHUNKS ((N_NODES + SCAN_B - 1) / SCAN_B)   // 196
#define NB      391                                   // dst buckets of 128 nodes
#define EPB     4096                                  // edges per pass-C block
#define EPG     1024                                  // edges per gemm128 block

struct __align__(8) H4 { __half2 a, b; };   // 4 halves = 8 bytes

typedef short bf16x8 __attribute__((ext_vector_type(8)));
typedef float f32x4  __attribute__((ext_vector_type(4)));

// ROCm 7.2 hip_fp16.h lacks __hmax2/__hmul2 — emit VOP3P packed ops directly.
__device__ __forceinline__ unsigned pk_max_f16(unsigned a, unsigned b) {
    unsigned r;
    asm("v_pk_max_f16 %0, %1, %2" : "=v"(r) : "v"(a), "v"(b));
    return r;
}
__device__ __forceinline__ unsigned pk_mul_f16(unsigned a, unsigned b) {
    unsigned r;
    asm("v_pk_mul_f16 %0, %1, %2" : "=v"(r) : "v"(a), "v"(b));
    return r;
}
__device__ __forceinline__ unsigned pkmax_xor(unsigned v, int o) {
    unsigned t = __shfl_xor((int)v, o, 64);
    return pk_max_f16(v, t);
}

// manual f32 -> bf16 round-to-nearest-even
__device__ __forceinline__ unsigned short f2bf(float f) {
    unsigned u = __float_as_uint(f);
    u += 0x7FFFu + ((u >> 16) & 1);
    return (unsigned short)(u >> 16);
}
__device__ __forceinline__ unsigned pk_bf(float a, float b) {
    return (unsigned)f2bf(a) | ((unsigned)f2bf(b) << 16);
}

// ---- CSR scan pass 1 --------------------------------------------------------
__device__ __forceinline__ int block_scan_incl(int v, int* wsum) {
    int lane = threadIdx.x & 63, w = threadIdx.x >> 6;
    int s = v;
#pragma unroll
    for (int d = 1; d < 64; d <<= 1) {
        int t = __shfl_up(s, d, 64);
        if (lane >= d) s += t;
    }
    if (lane == 63) wsum[w] = s;
    __syncthreads();
    int add = 0;
    for (int ww = 0; ww < (threadIdx.x >> 6); ++ww) add += wsum[ww];
    return s + add;
}

__global__ void k_scan1(const int* __restrict__ deg, int* __restrict__ rowptr,
                        int* __restrict__ partials) {
    __shared__ int wsum[4];
    int i = blockIdx.x * SCAN_B + threadIdx.x;
    int v = (i < N_NODES) ? deg[i] + 1 : 0;      // +1 = self loop
    int s = block_scan_incl(v, wsum);
    if (i < N_NODES) rowptr[i] = s - v;          // block-local exclusive
    if (threadIdx.x == SCAN_B - 1) partials[blockIdx.x] = s;
}

// ---- scan finalize: merges scan2 + scan3 + bucket_init ---------------------
__global__ void k_scan_fin(const int* __restrict__ partials, int* __restrict__ rowptr,
                           int* __restrict__ bcursor) {
    __shared__ int sp[SCAN_B];
    __shared__ int wsum[4];
    int t = threadIdx.x, b = blockIdx.x;
    int v = (t < N_CHUNKS) ? partials[t] : 0;
    int s = block_scan_incl(v, wsum);
    sp[t] = s - v;                               // exclusive prefix of partials
    __syncthreads();
    int add = sp[b];
    int i = b * SCAN_B + t;
    int r = 0;
    if (i < N_NODES) {
        r = rowptr[i] + add;
        rowptr[i] = r;
    }
    if (b == 0 && t == 0) rowptr[N_NODES] = E_TOT;
    if (t == 0)   bcursor[2 * b]     = r - ((2 * b) << 7);
    if (t == 128 && i < N_NODES) bcursor[2 * b + 1] = r - ((2 * b + 1) << 7);
}

// ---- pass C: bucket-grouping scatter (packed u32 pairs) --------------------
__global__ __launch_bounds__(256) void k_bucket_scatter(
        const unsigned* __restrict__ pairs_in, int* __restrict__ bcursor,
        unsigned* __restrict__ pairs_bkt) {
    __shared__ int counts[512];
    __shared__ int gbase[512];
    int t = threadIdx.x;
    counts[t] = 0; counts[t + 256] = 0;
    __syncthreads();
    int base = blockIdx.x * EPB;
    int nEdge = min(EPB, N_EDGES - base);
    unsigned pr[16];
    int rk[16], bk[16];
#define LOADI(i) { int idx = t + (i) * 256;                             \
        if (idx < nEdge) { pr[i] = pairs_in[base + idx];                \
            bk[i] = (pr[i] & 0xFFFF) >> 7;                              \
            rk[i] = atomicAdd(&counts[bk[i]], 1); } }
    LOADI(0) LOADI(1) LOADI(2) LOADI(3) LOADI(4) LOADI(5) LOADI(6) LOADI(7)
    LOADI(8) LOADI(9) LOADI(10) LOADI(11) LOADI(12) LOADI(13) LOADI(14) LOADI(15)
#undef LOADI
    __syncthreads();
    if (counts[t])       gbase[t]       = atomicAdd(&bcursor[t], counts[t]);
    if (counts[t + 256]) gbase[t + 256] = atomicAdd(&bcursor[t + 256], counts[t + 256]);
    __syncthreads();
#define STOREI(i) { int idx = t + (i) * 256;                            \
        if (idx < nEdge) pairs_bkt[gbase[bk[i]] + rk[i]] = pr[i]; }
    STOREI(0) STOREI(1) STOREI(2) STOREI(3) STOREI(4) STOREI(5) STOREI(6) STOREI(7)
    STOREI(8) STOREI(9) STOREI(10) STOREI(11) STOREI(12) STOREI(13) STOREI(14) STOREI(15)
#undef STOREI
}

// ---- pass D: within-bucket placement (LDS cursors, L2-resident writes) -----
__global__ __launch_bounds__(256) void k_bucket_place(
        const unsigned* __restrict__ pairs_bkt, const int* __restrict__ rowptr,
        int* __restrict__ src_sorted) {
    __shared__ int cur[128];
    int b = blockIdx.x, t = threadIdx.x;
    int d0 = b << 7;
    int dEnd = min(d0 + 128, N_NODES);
    if (t < 128) {
        int d = d0 + t;
        if (d < dEnd) {
            int r = rowptr[d];
            src_sorted[r] = d;            // self loop (order within segment free)
            cur[t] = r + 1;
        }
    }
    __syncthreads();
    int pbase = rowptr[d0] - d0;
    int pend  = rowptr[dEnd] - dEnd;
    for (int idx = pbase + t; idx < pend; idx += 256) {
        unsigned p = pairs_bkt[idx];
        int pos = atomicAdd(&cur[(p & 0xFFFF) - d0], 1);
        src_sorted[pos] = (int)(p >> 16);
    }
}

// ---- MFMA GEMM: WhH(fp16) = x@W (+ alpha dots; DOCONV: + edge convert) -----
// INBF16: x is bf16[N][64] (h_mid) -> raw 16B staging, no conversion.
template<int K, int DOCONV, int INBF16>
__global__ __launch_bounds__(256) void k_gemm_alpha(
        const void* __restrict__ xv, const float* __restrict__ W,
        const float* __restrict__ aW,
        H4* __restrict__ WhH,
        float* __restrict__ alpha_s, float* __restrict__ alpha_t,
        const void* ei, unsigned* __restrict__ pairs, int* __restrict__ deg) {
    __shared__ unsigned short xb[64][K + 8];
    __shared__ unsigned short wt[64][K + 8];
    __shared__ int s_is32;
    int tid = threadIdx.x;
    int rowBase = blockIdx.x * 64;

    if (INBF16) {
        int rr = tid >> 2;
        int kc = (tid & 3) * 16;                 // 16 bf16 = 32B per thread
        const unsigned short* xr = (const unsigned short*)xv
            + (size_t)min(rowBase + rr, N_NODES - 1) * 64 + kc;
        *(uint4*)&xb[rr][kc]     = *(const uint4*)xr;
        *(uint4*)&xb[rr][kc + 8] = *(const uint4*)(xr + 8);
    } else {
        int rr = tid >> 2;
        int kc = (tid & 3) * (K / 4);
        const float* xr = (const float*)xv + (size_t)min(rowBase + rr, N_NODES - 1) * K + kc;
        unsigned* dst = (unsigned*)&xb[rr][kc];
#pragma unroll
        for (int j = 0; j < K / 4; j += 8) {
            float4 v0 = *(const float4*)(xr + j);
            float4 v1 = *(const float4*)(xr + j + 4);
            dst[j / 2 + 0] = pk_bf(v0.x, v0.y);
            dst[j / 2 + 1] = pk_bf(v0.z, v0.w);
            dst[j / 2 + 2] = pk_bf(v1.x, v1.y);
            dst[j / 2 + 3] = pk_bf(v1.z, v1.w);
        }
    }
    for (int i = tid; i < K * 64; i += 256) {
        int k = i >> 6, n = i & 63;
        wt[n][k] = f2bf(W[i]);
    }
    if (DOCONV && tid == 0) s_is32 = 0;
    __syncthreads();

    int w = tid >> 6, lane = tid & 63;
    int la = lane & 15, hi = lane >> 4;

    f32x4 acc[4];
#pragma unroll
    for (int c = 0; c < 4; ++c) acc[c] = (f32x4){0.f, 0.f, 0.f, 0.f};

#pragma unroll
    for (int t = 0; t < K / 32; ++t) {
        int k0 = t * 32 + hi * 8;
        bf16x8 af = *(const bf16x8*)&xb[w * 16 + la][k0];
#pragma unroll
        for (int c = 0; c < 4; ++c) {
            bf16x8 bfr = *(const bf16x8*)&wt[c * 16 + la][k0];
            acc[c] = __builtin_amdgcn_mfma_f32_16x16x32_bf16(af, bfr, acc[c], 0, 0, 0);
        }
    }

    float as4[4], at4[4];
#pragma unroll
    for (int c = 0; c < 4; ++c) {
        as4[c] = aW[c * 16 + la];
        at4[c] = aW[64 + c * 16 + la];
    }
#pragma unroll
    for (int r = 0; r < 4; ++r) {
        int row = rowBase + w * 16 + hi * 4 + r;
        float ps = acc[0][r] * as4[0] + acc[1][r] * as4[1]
                 + acc[2][r] * as4[2] + acc[3][r] * as4[3];
        float pt = acc[0][r] * at4[0] + acc[1][r] * at4[1]
                 + acc[2][r] * at4[2] + acc[3][r] * at4[3];
#pragma unroll
        for (int o = 1; o < 16; o <<= 1) {
            ps += __shfl_xor(ps, o, 64);
            pt += __shfl_xor(pt, o, 64);
        }
        if (row < N_NODES) {
            __half* wr = (__half*)&WhH[(size_t)row * 16];
#pragma unroll
            for (int c = 0; c < 4; ++c)
                wr[c * 16 + la] = __float2half(acc[c][r]);
            if (la == 0) { alpha_s[row] = ps; alpha_t[row] = pt; }
        }
    }

    // fused edge convert (packed u32) + deg histogram (layer-1 only)
    if (DOCONV) {
        const int* p32 = (const int*)ei;
        if (p32[2 * tid + 1] != 0) atomicOr(&s_is32, 1);
        __syncthreads();
        int is32 = s_is32;
        int base = blockIdx.x * EPG;
#pragma unroll
        for (int i = 0; i < EPG / 256; ++i) {
            int e = base + tid + i * 256;
            if (e < N_EDGES) {
                int s, d;
                if (is32) {
                    s = p32[e]; d = p32[N_EDGES + e];
                } else {
                    const long long* p64 = (const long long*)ei;
                    s = (int)p64[e]; d = (int)p64[N_EDGES + e];
                }
                pairs[e] = ((unsigned)s << 16) | (unsigned)d;
                atomicAdd(&deg[d], 1);
            }
        }
    }
}

// ---- slow path helper (deg > 64): chunked two-pass, scalar fp16 gather -----
__device__ void slow_node(int rs, int re, const int* __restrict__ src_sorted,
                          const float* __restrict__ alpha_s, float at,
                          const H4* __restrict__ WhH, int lane, int fl2,
                          float& z, unsigned vm[4]) {
    float m = -INFINITY;
    for (int base = rs; base < re; base += 64) {
        int idx = base + lane;
        float sim = -INFINITY;
        if (idx < re) {
            int sv = src_sorted[idx];
            float t = alpha_s[sv] + at;
            sim = t > 0.f ? t : 0.2f * t;
        }
#pragma unroll
        for (int o = 32; o; o >>= 1) sim = fmaxf(sim, __shfl_xor(sim, o, 64));
        m = fmaxf(m, sim);
    }
    z = 0.f;
    float vsc = -INFINITY;
    for (int base = rs; base < re; base += 64) {
        int idx = base + lane;
        int cnt = min(64, re - base);
        int svv = 0;
        float ev = 0.f;
        if (idx < re) {
            svv = src_sorted[idx];
            float t = alpha_s[svv] + at;
            t = t > 0.f ? t : 0.2f * t;
            ev = __expf(t - m);
        }
        float sz = ev;
#pragma unroll
        for (int o = 32; o; o >>= 1) sz += __shfl_xor(sz, o, 64);
        z += sz;
        for (int j = 0; j < cnt; ++j) {
            int sj = __shfl(svv, j, 64);
            float ej = __shfl(ev, j, 64);
            float v = __half2float(((const __half*)WhH)[(size_t)sj * 64 + lane]);
            vsc = fmaxf(vsc, ej * v);
        }
    }
#pragma unroll
    for (int q = 0; q < 4; ++q) {
        float a0 = __shfl(vsc, fl2 * 8 + 2 * q, 64);
        float a1 = __shfl(vsc, fl2 * 8 + 2 * q + 1, 64);
        __half2 p = __floats2half2_rn(a0, a1);
        vm[q] = *(unsigned*)&p;
    }
}

// ---- per-dst-node fused aggregation (R11 form; HEAD=0 writes bf16 h_mid) ---
template<int HEAD>
__global__ void k_node_aggr(const int* __restrict__ rowptr, const int* __restrict__ src_sorted,
                            const float* __restrict__ alpha_s, const float* __restrict__ alpha_t,
                            const float* __restrict__ ab, const H4* __restrict__ WhH,
                            const float* __restrict__ bias,
                            const float* __restrict__ Wo, const float* __restrict__ bo,
                            void* __restrict__ outp) {
    __shared__ float sWo[HEAD ? 64 * N_CLS : 1];
    __shared__ float sh[HEAD ? 8 * 64 : 1];
    int lane = threadIdx.x, w = threadIdx.y;
    if (HEAD) {
        int tid = w * 64 + lane;
        for (int i = tid; i < 64 * N_CLS; i += 256) sWo[i] = Wo[i];
    }
    int dA = blockIdx.x * 8 + w * 2;       // grid exact: 6250*8 == N_NODES
    int dB = dA + 1;
    int rsA = rowptr[dA], reA = rowptr[dA + 1];
    int rsB = rowptr[dB], reB = rowptr[dB + 1];
    int degA = reA - rsA, degB = reB - rsB;
    float abv = ab[0];
    float atA = alpha_t[dA] + abv;
    float atB = alpha_t[dB] + abv;
    int g2 = lane >> 3, fl2 = lane & 7;
    const char* whb = (const char*)WhH;

    float zA, zB;
    unsigned vmA[4], vmB[4];

    if (degA <= 64 && degB <= 64) {
        // --- dual fast path ---
        int svA = src_sorted[rsA + min(lane, degA - 1)];
        int svB = src_sorted[rsB + min(lane, degB - 1)];
        float tA = alpha_s[svA] + atA; tA = tA > 0.f ? tA : 0.2f * tA;
        float tB = alpha_s[svB] + atB; tB = tB > 0.f ? tB : 0.2f * tB;
        float evA = __expf(tA);            // no max-subtract: |t| is O(1)
        float evB = __expf(tB);
        float zzA = (lane < degA) ? evA : 0.f;
        float zzB = (lane < degB) ? evB : 0.f;
#pragma unroll
        for (int o = 32; o; o >>= 1) {
            zzA += __shfl_xor(zzA, o, 64);
            zzB += __shfl_xor(zzB, o, 64);
        }
        zA = zzA; zB = zzB;
        int ofsA = svA * 128, ofsB = svB * 128;   // byte offsets of fp16 rows

        const unsigned NEGINF2 = 0xFC00FC00u;     // {-inf,-inf} fp16
        unsigned vA0 = NEGINF2, vA1 = NEGINF2, vA2 = NEGINF2, vA3 = NEGINF2;
        unsigned vB0 = NEGINF2, vB1 = NEGINF2, vB2 = NEGINF2, vB3 = NEGINF2;
#define ROUND(ev, ofs, deg, v0, v1, v2, v3, r) { \
        int j = (r) * 8 + g2; j = j < (deg) ? j : (deg) - 1;              \
        float ej = __shfl((ev), j, 64);                                   \
        int ro = __shfl((ofs), j, 64);                                    \
        uint4 hv = *(const uint4*)(whb + ro + fl2 * 16);                  \
        __half2 ejh = __float2half2_rn(ej);                               \
        unsigned ej2 = *(unsigned*)&ejh;                                  \
        v0 = pk_max_f16(v0, pk_mul_f16(ej2, hv.x));                       \
        v1 = pk_max_f16(v1, pk_mul_f16(ej2, hv.y));                       \
        v2 = pk_max_f16(v2, pk_mul_f16(ej2, hv.z));                       \
        v3 = pk_max_f16(v3, pk_mul_f16(ej2, hv.w)); }
#define RA(r) ROUND(evA, ofsA, degA, vA0, vA1, vA2, vA3, r)
#define RB(r) ROUND(evB, ofsB, degB, vB0, vB1, vB2, vB3, r)

        RA(0) RB(0) RA(1) RB(1)
        if (degA > 16) { RA(2) RA(3) }
        if (degB > 16) { RB(2) RB(3) }
        if (degA > 32) { RA(4) RA(5) RA(6) RA(7) }
        if (degB > 32) { RB(4) RB(5) RB(6) RB(7) }
#undef RA
#undef RB
#undef ROUND
#pragma unroll
        for (int o = 8; o <= 32; o <<= 1) {
            vA0 = pkmax_xor(vA0, o); vA1 = pkmax_xor(vA1, o);
            vA2 = pkmax_xor(vA2, o); vA3 = pkmax_xor(vA3, o);
            vB0 = pkmax_xor(vB0, o); vB1 = pkmax_xor(vB1, o);
            vB2 = pkmax_xor(vB2, o); vB3 = pkmax_xor(vB3, o);
        }
        vmA[0] = vA0; vmA[1] = vA1; vmA[2] = vA2; vmA[3] = vA3;
        vmB[0] = vB0; vmB[1] = vB1; vmB[2] = vB2; vmB[3] = vB3;
    } else {
        slow_node(rsA, reA, src_sorted, alpha_s, atA, WhH, lane, fl2, zA, vmA);
        slow_node(rsB, reB, src_sorted, alpha_s, atB, WhH, lane, fl2, zB, vmB);
    }

    // epilogue per node: h = vmax/z + bias, relu.
    float4 b0 = *(const float4*)(bias + fl2 * 8);
    float4 b1 = *(const float4*)(bias + fl2 * 8 + 4);
    float rzA = 1.0f / zA, rzB = 1.0f / zB;
    float h8A[8], h8B[8];
#pragma unroll
    for (int q = 0; q < 4; ++q) {
        float2 fa = __half22float2(*(__half2*)&vmA[q]);
        float2 fb = __half22float2(*(__half2*)&vmB[q]);
        h8A[2 * q] = fa.x; h8A[2 * q + 1] = fa.y;
        h8B[2 * q] = fb.x; h8B[2 * q + 1] = fb.y;
    }
    float bias8[8] = { b0.x, b0.y, b0.z, b0.w, b1.x, b1.y, b1.z, b1.w };
#pragma unroll
    for (int q = 0; q < 8; ++q) {
        h8A[q] = fmaxf(h8A[q] * rzA + bias8[q], 0.f);
        h8B[q] = fmaxf(h8B[q] * rzB + bias8[q], 0.f);
    }

    if (!HEAD) {
        // write bf16 h_mid rows (128B each); g2==0 -> node A, g2==1 -> node B
        unsigned short* hm = (unsigned short*)outp;
        if (g2 == 0) {
            uint4 v;
            v.x = pk_bf(h8A[0], h8A[1]); v.y = pk_bf(h8A[2], h8A[3]);
            v.z = pk_bf(h8A[4], h8A[5]); v.w = pk_bf(h8A[6], h8A[7]);
            *(uint4*)(hm + (size_t)dA * 64 + fl2 * 8) = v;
        } else if (g2 == 1) {
            uint4 v;
            v.x = pk_bf(h8B[0], h8B[1]); v.y = pk_bf(h8B[2], h8B[3]);
            v.z = pk_bf(h8B[4], h8B[5]); v.w = pk_bf(h8B[6], h8B[7]);
            *(uint4*)(hm + (size_t)dB * 64 + fl2 * 8) = v;
        }
    } else {
        float* op = (float*)outp;
        if (g2 == 0) {
            float* sp = sh + (2 * w) * 64 + fl2 * 8;
            *(float4*)sp = make_float4(h8A[0], h8A[1], h8A[2], h8A[3]);
            *(float4*)(sp + 4) = make_float4(h8A[4], h8A[5], h8A[6], h8A[7]);
        } else if (g2 == 1) {
            float* sp = sh + (2 * w + 1) * 64 + fl2 * 8;
            *(float4*)sp = make_float4(h8B[0], h8B[1], h8B[2], h8B[3]);
            *(float4*)(sp + 4) = make_float4(h8B[4], h8B[5], h8B[6], h8B[7]);
        }
        __syncthreads();
#pragma unroll
        for (int n = 0; n < 2; ++n) {
            int dd = dA + n;
            const float* hrow = sh + (2 * w + n) * 64;
            float logit = -INFINITY;
            if (lane < N_CLS) {
                float acc = bo[lane];
#pragma unroll
                for (int k = 0; k < 64; ++k)
                    acc = fmaf(hrow[k], sWo[k * N_CLS + lane], acc);
                logit = acc;
            }
            float mx = logit;
#pragma unroll
            for (int o = 32; o; o >>= 1) mx = fmaxf(mx, __shfl_xor(mx, o, 64));
            float ex = (lane < N_CLS) ? __expf(logit - mx) : 0.f;
            float sm = ex;
#pragma unroll
            for (int o = 32; o; o >>= 1) sm += __shfl_xor(sm, o, 64);
            float lse = mx + __logf(sm);
            if (lane < N_CLS) op[(size_t)dd * N_CLS + lane] = logit - lse;
        }
    }
}

extern "C" void kernel_launch(void* const* d_in, const int* in_sizes, int n_in,
                              void* d_out, int out_size, void* d_ws, size_t ws_size,
                              hipStream_t stream) {
    const float* x   = (const float*)d_in[0];
    const void*  ei  = d_in[1];
    const float* W1  = (const float*)d_in[2];
    const float* aW1 = (const float*)d_in[3];
    const float* ab1 = (const float*)d_in[4];
    const float* b1  = (const float*)d_in[5];
    const float* W2  = (const float*)d_in[6];
    const float* aW2 = (const float*)d_in[7];
    const float* ab2 = (const float*)d_in[8];
    const float* b2  = (const float*)d_in[9];
    const float* Wo  = (const float*)d_in[10];
    const float* bo  = (const float*)d_in[11];
    float* out = (float*)d_out;

    char* ws = (char*)d_ws;
    size_t off = 0;
    auto alloc = [&](size_t bytes) {
        void* p = ws + off;
        off += (bytes + 255) & ~(size_t)255;
        return p;
    };
    unsigned* pairs     = (unsigned*)alloc((size_t)N_EDGES * 4);
    unsigned* pairs_bkt = (unsigned*)alloc((size_t)N_EDGES * 4);
    int*   deg        = (int*)alloc((size_t)N_NODES * 4);
    int*   rowptr     = (int*)alloc((size_t)(N_NODES + 1) * 4);
    int*   bcursor    = (int*)alloc((size_t)512 * 4);
    int*   partials   = (int*)alloc((size_t)SCAN_B * 4);
    int*   src_sorted = (int*)alloc((size_t)E_TOT * 4);
    H4*    WhH        = (H4*)alloc((size_t)N_NODES * 64 * 2);
    unsigned short* h_mid = (unsigned short*)alloc((size_t)N_NODES * 64 * 2);
    float* alpha_s    = (float*)alloc((size_t)N_NODES * 4);
    float* alpha_t    = (float*)alloc((size_t)N_NODES * 4);

    const int B = 256;
    int gPassC = (N_EDGES + EPB - 1) / EPB;   // 196
    dim3 blk2(64, 4);
    int gRow  = N_NODES / 8;            // 6250, exact (2 nodes/wave)
    int gGemm = (N_NODES + 63) / 64;    // 782 (782*EPG >= N_EDGES for convert)

    hipMemsetAsync(deg, 0, (size_t)N_NODES * 4, stream);

    // ---- layer-1 GEMM fused with edge convert + deg histogram
    k_gemm_alpha<128, 1, 0><<<gGemm, 256, 0, stream>>>(x, W1, aW1, WhH, alpha_s, alpha_t,
                                                       ei, pairs, deg);
    // ---- CSR build
    k_scan1<<<N_CHUNKS, SCAN_B, 0, stream>>>(deg, rowptr, partials);
    k_scan_fin<<<N_CHUNKS, SCAN_B, 0, stream>>>(partials, rowptr, bcursor);
    k_bucket_scatter<<<gPassC, B, 0, stream>>>(pairs, bcursor, pairs_bkt);
    k_bucket_place<<<NB, B, 0, stream>>>(pairs_bkt, rowptr, src_sorted);

    // ---- layer 1 aggregation (writes bf16 h_mid)
    k_node_aggr<0><<<gRow, blk2, 0, stream>>>(rowptr, src_sorted, alpha_s, alpha_t,
                                              ab1, WhH, b1, nullptr, nullptr, h_mid);

    // ---- layer 2 (+ fused output head)
    k_gemm_alpha<64, 0, 1><<<gGemm, 256, 0, stream>>>(h_mid, W2, aW2, WhH, alpha_s, alpha_t,
                                                      nullptr, nullptr, nullptr);
    k_node_aggr<1><<<gRow, blk2, 0, stream>>>(rowptr, src_sorted, alpha_s, alpha_t,
                                              ab2, WhH, b2, Wo, bo, out);
}